// Round 1
// baseline (501.219 us; speedup 1.0000x reference)
//
#include <hip/hip_runtime.h>

#define SEQ 4096
#define HID 512
#define NB  4
#define N3  1536

typedef _Float16 half_t;
typedef __attribute__((ext_vector_type(8))) _Float16 half8;
typedef __attribute__((ext_vector_type(4))) float f32x4;

#define GLOAD_LDS16(gp, lp) __builtin_amdgcn_global_load_lds((gp), (lp), 16, 0, 0)

__device__ __forceinline__ float fmax4(float4 v) {
  return fmaxf(fmaxf(v.x, v.y), fmaxf(v.z, v.w));
}

// ---------------- convert x (f32) -> f16 ----------------
__global__ void k_cvt(const float* __restrict__ x, half_t* __restrict__ xh, int n4) {
  int i = blockIdx.x * blockDim.x + threadIdx.x;
  int stride = gridDim.x * blockDim.x;
  for (; i < n4; i += stride) {
    float4 v = reinterpret_cast<const float4*>(x)[i];
    union { half_t h[4]; short4 s; } u;
    u.h[0] = (half_t)v.x; u.h[1] = (half_t)v.y;
    u.h[2] = (half_t)v.z; u.h[3] = (half_t)v.w;
    reinterpret_cast<short4*>(xh)[i] = u.s;
  }
}

// ---------------- W [512][1536] f32 -> Wt [1536][512] f16 ----------------
__global__ void k_tw(const float* __restrict__ W, half_t* __restrict__ Wt) {
  __shared__ half_t tile[64][65];
  const int n0 = blockIdx.x * 64;
  const int k0 = blockIdx.y * 64;
  const int tx = threadIdx.x & 63, ty = threadIdx.x >> 6;
#pragma unroll
  for (int i = 0; i < 64; i += 4)
    tile[ty + i][tx] = (half_t)W[(size_t)(k0 + ty + i) * N3 + n0 + tx];
  __syncthreads();
#pragma unroll
  for (int i = 0; i < 64; i += 4)
    Wt[(size_t)(n0 + ty + i) * HID + k0 + tx] = tile[tx][ty + i];
}

// ---------------- QKV projection GEMM ----------------
// C[16384][1536] = xh[16384][512] @ Wt[1536][512]^T + bias, scatter to Q(scaled)/K/Vt f16
__launch_bounds__(256)
__global__ void k_qkv(const half_t* __restrict__ xh, const half_t* __restrict__ Wt,
                      const float* __restrict__ bias,
                      half_t* __restrict__ Qh, half_t* __restrict__ Kh,
                      half_t* __restrict__ Vt) {
  __shared__ half_t sA[128 * 32];
  __shared__ half_t sB[128 * 32];
  const int t = threadIdx.x;
  const int m0 = blockIdx.y * 128;
  const int n0 = blockIdx.x * 128;
  const int lane = t & 63, wid = t >> 6;
  const int wr = (wid >> 1) * 64, wc = (wid & 1) * 64;
  const int lrow = lane & 15, lks = lane >> 4;
  const int s1 = t, s2 = t + 256;
  const int ar1 = s1 >> 2, ac1 = (s1 & 3) * 8;
  const int ar2 = s2 >> 2, ac2 = (s2 & 3) * 8;

  f32x4 acc[4][4] = {};

  for (int k0 = 0; k0 < HID; k0 += 32) {
    __syncthreads();
    GLOAD_LDS16(xh + (size_t)(m0 + ar1) * HID + k0 + ac1, &sA[s1 * 8]);
    GLOAD_LDS16(xh + (size_t)(m0 + ar2) * HID + k0 + ac2, &sA[s2 * 8]);
    GLOAD_LDS16(Wt + (size_t)(n0 + ar1) * HID + k0 + ac1, &sB[s1 * 8]);
    GLOAD_LDS16(Wt + (size_t)(n0 + ar2) * HID + k0 + ac2, &sB[s2 * 8]);
    __syncthreads();
    half8 a[4], b[4];
#pragma unroll
    for (int m = 0; m < 4; ++m)
      a[m] = *reinterpret_cast<const half8*>(&sA[(wr + m * 16 + lrow) * 32 + lks * 8]);
#pragma unroll
    for (int n = 0; n < 4; ++n)
      b[n] = *reinterpret_cast<const half8*>(&sB[(wc + n * 16 + lrow) * 32 + lks * 8]);
#pragma unroll
    for (int m = 0; m < 4; ++m)
#pragma unroll
      for (int n = 0; n < 4; ++n)
        acc[m][n] = __builtin_amdgcn_mfma_f32_16x16x32_f16(a[m], b[n], acc[m][n], 0, 0, 0);
  }

  const float scale = 0.04419417382415922f;  // 1/sqrt(512)
  const int region = n0 >> 9;  // 0=Q, 1=K, 2=V (uniform per block: 512 % 128 == 0)
#pragma unroll
  for (int m = 0; m < 4; ++m) {
#pragma unroll
    for (int n = 0; n < 4; ++n) {
      const int col = n0 + wc + n * 16 + lrow;
#pragma unroll
      for (int r = 0; r < 4; ++r) {
        const int row = m0 + wr + m * 16 + lks * 4 + r;  // global M row [0,16384)
        float v = acc[m][n][r] + bias[col];
        if (region == 0) {
          Qh[(size_t)row * HID + col] = (half_t)(v * scale);
        } else if (region == 1) {
          Kh[(size_t)row * HID + (col - 512)] = (half_t)v;
        } else {
          const int bb = row >> 12, ml = row & (SEQ - 1);
          Vt[((size_t)bb * HID + (col - 1024)) * SEQ + ml] = (half_t)v;
        }
      }
    }
  }
}

// ---------------- scores = Q @ K^T (scale pre-folded into Q) ----------------
__launch_bounds__(256)
__global__ void k_qk(const half_t* __restrict__ Qh, const half_t* __restrict__ Kh,
                     float* __restrict__ S) {
  __shared__ half_t sA[128 * 32];
  __shared__ half_t sB[128 * 32];
  const int t = threadIdx.x;
  const int bz = blockIdx.z;
  const half_t* A = Qh + (size_t)bz * SEQ * HID;
  const half_t* B = Kh + (size_t)bz * SEQ * HID;
  float* C = S + (size_t)bz * SEQ * SEQ;
  const int m0 = blockIdx.y * 128;
  const int n0 = blockIdx.x * 128;
  const int lane = t & 63, wid = t >> 6;
  const int wr = (wid >> 1) * 64, wc = (wid & 1) * 64;
  const int lrow = lane & 15, lks = lane >> 4;
  const int s1 = t, s2 = t + 256;
  const int ar1 = s1 >> 2, ac1 = (s1 & 3) * 8;
  const int ar2 = s2 >> 2, ac2 = (s2 & 3) * 8;

  f32x4 acc[4][4] = {};

  for (int k0 = 0; k0 < HID; k0 += 32) {
    __syncthreads();
    GLOAD_LDS16(A + (size_t)(m0 + ar1) * HID + k0 + ac1, &sA[s1 * 8]);
    GLOAD_LDS16(A + (size_t)(m0 + ar2) * HID + k0 + ac2, &sA[s2 * 8]);
    GLOAD_LDS16(B + (size_t)(n0 + ar1) * HID + k0 + ac1, &sB[s1 * 8]);
    GLOAD_LDS16(B + (size_t)(n0 + ar2) * HID + k0 + ac2, &sB[s2 * 8]);
    __syncthreads();
    half8 a[4], b[4];
#pragma unroll
    for (int m = 0; m < 4; ++m)
      a[m] = *reinterpret_cast<const half8*>(&sA[(wr + m * 16 + lrow) * 32 + lks * 8]);
#pragma unroll
    for (int n = 0; n < 4; ++n)
      b[n] = *reinterpret_cast<const half8*>(&sB[(wc + n * 16 + lrow) * 32 + lks * 8]);
#pragma unroll
    for (int m = 0; m < 4; ++m)
#pragma unroll
      for (int n = 0; n < 4; ++n)
        acc[m][n] = __builtin_amdgcn_mfma_f32_16x16x32_f16(a[m], b[n], acc[m][n], 0, 0, 0);
  }

#pragma unroll
  for (int m = 0; m < 4; ++m)
#pragma unroll
    for (int n = 0; n < 4; ++n)
#pragma unroll
      for (int r = 0; r < 4; ++r)
        C[(size_t)(m0 + wr + m * 16 + lks * 4 + r) * SEQ + (n0 + wc + n * 16 + lrow)] =
            acc[m][n][r];
}

// ---------------- row softmax, in place on f32 scores ----------------
__launch_bounds__(256)
__global__ void k_softmax(float* __restrict__ attn) {
  float* p = attn + (size_t)blockIdx.x * SEQ;
  const int t = threadIdx.x;
  float4 v[4];
  float mx = -3.4028235e38f;
#pragma unroll
  for (int i = 0; i < 4; ++i) {
    v[i] = reinterpret_cast<float4*>(p)[t + i * 256];
    mx = fmaxf(mx, fmax4(v[i]));
  }
#pragma unroll
  for (int o = 32; o > 0; o >>= 1) mx = fmaxf(mx, __shfl_xor(mx, o));
  __shared__ float redm[4], reds[4];
  if ((t & 63) == 0) redm[t >> 6] = mx;
  __syncthreads();
  mx = fmaxf(fmaxf(redm[0], redm[1]), fmaxf(redm[2], redm[3]));
  float sum = 0.f;
#pragma unroll
  for (int i = 0; i < 4; ++i) {
    v[i].x = expf(v[i].x - mx);
    v[i].y = expf(v[i].y - mx);
    v[i].z = expf(v[i].z - mx);
    v[i].w = expf(v[i].w - mx);
    sum += (v[i].x + v[i].y) + (v[i].z + v[i].w);
  }
#pragma unroll
  for (int o = 32; o > 0; o >>= 1) sum += __shfl_xor(sum, o);
  if ((t & 63) == 0) reds[t >> 6] = sum;
  __syncthreads();
  sum = (reds[0] + reds[1]) + (reds[2] + reds[3]);
  const float inv = 1.0f / sum;
#pragma unroll
  for (int i = 0; i < 4; ++i) {
    v[i].x *= inv; v[i].y *= inv; v[i].z *= inv; v[i].w *= inv;
    reinterpret_cast<float4*>(p)[t + i * 256] = v[i];
  }
}

// ---------------- opt = attn @ V  (A: f32 attn reg-staged to f16; B = Vt[n][k]) --------
__launch_bounds__(256)
__global__ void k_pv(const float* __restrict__ P, const half_t* __restrict__ Vt,
                     float* __restrict__ O) {
  __shared__ half_t sA[128 * 32];
  __shared__ half_t sB[128 * 32];
  const int t = threadIdx.x;
  const int bz = blockIdx.z;
  const float* A = P + (size_t)bz * SEQ * SEQ;
  const half_t* B = Vt + (size_t)bz * HID * SEQ;
  float* C = O + (size_t)bz * SEQ * HID;
  const int m0 = blockIdx.y * 128;
  const int n0 = blockIdx.x * 128;
  const int lane = t & 63, wid = t >> 6;
  const int wr = (wid >> 1) * 64, wc = (wid & 1) * 64;
  const int lrow = lane & 15, lks = lane >> 4;
  const int s1 = t, s2 = t + 256;
  const int ar1 = s1 >> 2, ac1 = (s1 & 3) * 8;
  const int ar2 = s2 >> 2, ac2 = (s2 & 3) * 8;

  f32x4 acc[4][4] = {};

  for (int k0 = 0; k0 < SEQ; k0 += 32) {
    __syncthreads();
    GLOAD_LDS16(B + (size_t)(n0 + ar1) * SEQ + k0 + ac1, &sB[s1 * 8]);
    GLOAD_LDS16(B + (size_t)(n0 + ar2) * SEQ + k0 + ac2, &sB[s2 * 8]);
    {
      const float* g1 = A + (size_t)(m0 + ar1) * SEQ + k0 + ac1;
      float4 u0 = reinterpret_cast<const float4*>(g1)[0];
      float4 u1 = reinterpret_cast<const float4*>(g1)[1];
      half8 w;
      w[0] = (half_t)u0.x; w[1] = (half_t)u0.y; w[2] = (half_t)u0.z; w[3] = (half_t)u0.w;
      w[4] = (half_t)u1.x; w[5] = (half_t)u1.y; w[6] = (half_t)u1.z; w[7] = (half_t)u1.w;
      *reinterpret_cast<half8*>(&sA[s1 * 8]) = w;
      const float* g2 = A + (size_t)(m0 + ar2) * SEQ + k0 + ac2;
      u0 = reinterpret_cast<const float4*>(g2)[0];
      u1 = reinterpret_cast<const float4*>(g2)[1];
      w[0] = (half_t)u0.x; w[1] = (half_t)u0.y; w[2] = (half_t)u0.z; w[3] = (half_t)u0.w;
      w[4] = (half_t)u1.x; w[5] = (half_t)u1.y; w[6] = (half_t)u1.z; w[7] = (half_t)u1.w;
      *reinterpret_cast<half8*>(&sA[s2 * 8]) = w;
    }
    __syncthreads();
    half8 a[4], b[4];
#pragma unroll
    for (int m = 0; m < 4; ++m)
      a[m] = *reinterpret_cast<const half8*>(&sA[(wr + m * 16 + lrow) * 32 + lks * 8]);
#pragma unroll
    for (int n = 0; n < 4; ++n)
      b[n] = *reinterpret_cast<const half8*>(&sB[(wc + n * 16 + lrow) * 32 + lks * 8]);
#pragma unroll
    for (int m = 0; m < 4; ++m)
#pragma unroll
      for (int n = 0; n < 4; ++n)
        acc[m][n] = __builtin_amdgcn_mfma_f32_16x16x32_f16(a[m], b[n], acc[m][n], 0, 0, 0);
  }

#pragma unroll
  for (int m = 0; m < 4; ++m)
#pragma unroll
    for (int n = 0; n < 4; ++n)
#pragma unroll
      for (int r = 0; r < 4; ++r)
        C[(size_t)(m0 + wr + m * 16 + lks * 4 + r) * HID + (n0 + wc + n * 16 + lrow)] =
            acc[m][n][r];
}

extern "C" void kernel_launch(void* const* d_in, const int* in_sizes, int n_in,
                              void* d_out, int out_size, void* d_ws, size_t ws_size,
                              hipStream_t stream) {
  const float* x = (const float*)d_in[0];     // [4,4096,512]
  const float* W = (const float*)d_in[1];     // [512,1536]
  const float* bias = (const float*)d_in[2];  // [1536]
  float* opt = (float*)d_out;                        // [4*4096*512]
  float* attn = opt + (size_t)NB * SEQ * HID;        // [4*4096*4096]

  half_t* xh = (half_t*)d_ws;                        // 16384*512
  half_t* Wt = xh + (size_t)NB * SEQ * HID;          // 1536*512
  half_t* Qh = Wt + (size_t)N3 * HID;                // 16384*512 (scale folded)
  half_t* Kh = Qh + (size_t)NB * SEQ * HID;          // 16384*512
  half_t* Vt = Kh + (size_t)NB * SEQ * HID;          // 4*[512][4096] transposed

  k_cvt<<<2048, 256, 0, stream>>>(x, xh, NB * SEQ * HID / 4);
  k_tw<<<dim3(N3 / 64, HID / 64), 256, 0, stream>>>(W, Wt);
  k_qkv<<<dim3(N3 / 128, NB * SEQ / 128), 256, 0, stream>>>(xh, Wt, bias, Qh, Kh, Vt);
  k_qk<<<dim3(SEQ / 128, SEQ / 128, NB), 256, 0, stream>>>(Qh, Kh, attn);
  k_softmax<<<NB * SEQ, 256, 0, stream>>>(attn);
  k_pv<<<dim3(HID / 128, SEQ / 128, NB), 256, 0, stream>>>(attn, Vt, opt);
}